// Round 1
// baseline (2615.397 us; speedup 1.0000x reference)
//
#include <hip/hip_runtime.h>
#include <hip/hip_bf16.h>
#include <cstdint>

#define DMODEL 768
#define NB 64        // batch
#define NHEAD 12
#define DHEAD 64
#define SEQLEN 512
#define NDOM 3
#define NBLK 2
#define FFNH 3072
#define NBROWS (NDOM*NB)   // 192

__device__ __forceinline__ float wsum(float v){
  #pragma unroll
  for (int o = 32; o; o >>= 1) v += __shfl_xor(v, o, 64);
  return v;
}
__device__ __forceinline__ float wmaxf(float v){
  #pragma unroll
  for (int o = 32; o; o >>= 1) v = fmaxf(v, __shfl_xor(v, o, 64));
  return v;
}
__device__ __forceinline__ float dot4f(float4 a, float4 b){
  return fmaf(a.x, b.x, fmaf(a.y, b.y, fmaf(a.z, b.z, a.w * b.w)));
}

// -------- LayerNorm: one wave per row of [rows, 768] --------
__global__ __launch_bounds__(256) void k_ln(const float* __restrict__ in,
    const float* __restrict__ w, const float* __restrict__ b,
    float* __restrict__ out, int rows){
  int gw = (blockIdx.x * 256 + threadIdx.x) >> 6;
  int lane = threadIdx.x & 63;
  if (gw >= rows) return;
  const float4* x4 = (const float4*)(in + (size_t)gw * DMODEL);
  float4 v0 = x4[lane], v1 = x4[64 + lane], v2 = x4[128 + lane];
  float s = v0.x+v0.y+v0.z+v0.w + v1.x+v1.y+v1.z+v1.w + v2.x+v2.y+v2.z+v2.w;
  float q = dot4f(v0,v0) + dot4f(v1,v1) + dot4f(v2,v2);
  s = wsum(s); q = wsum(q);
  float m = s * (1.0f / DMODEL);
  float var = q * (1.0f / DMODEL) - m * m;
  float r = rsqrtf(var + 1e-5f);
  const float4* w4 = (const float4*)w;
  const float4* b4 = (const float4*)b;
  float4* o4 = (float4*)(out + (size_t)gw * DMODEL);
  float4 vv[3] = {v0, v1, v2};
  #pragma unroll
  for (int seg = 0; seg < 3; ++seg){
    float4 ww = w4[seg*64 + lane], bb = b4[seg*64 + lane], x = vv[seg], o;
    o.x = (x.x - m) * r * ww.x + bb.x;
    o.y = (x.y - m) * r * ww.y + bb.y;
    o.z = (x.z - m) * r * ww.z + bb.z;
    o.w = (x.w - m) * r * ww.w + bb.w;
    o4[seg*64 + lane] = o;
  }
}

// -------- generic small GEMM: out[64, ncols] = act(A[64,K] @ W[ncols,K]^T + bias) --------
// thread = (bg, j), bg handles 8 batch rows; A loads are wave-uniform (scalarized).
// ACT: 0 none, 1 silu, 2 (acc/3 + bias)  ; RES: add residual res[o]
template<int K, int ACT, bool RES>
__global__ __launch_bounds__(256) void k_gemmT(const float* __restrict__ A,
    const float* __restrict__ W, const float* __restrict__ bias,
    const float* __restrict__ res, float* __restrict__ out, int ncols){
  int tid = blockIdx.x * 256 + threadIdx.x;
  if (tid >= 8 * ncols) return;
  int bg = tid / ncols; int j = tid - bg * ncols;
  const float4* w4 = (const float4*)(W + (size_t)j * K);
  const float4* a4 = (const float4*)(A + (size_t)bg * 8 * K);
  float acc[8] = {0,0,0,0,0,0,0,0};
  for (int i = 0; i < K/4; ++i){
    float4 wv = w4[i];
    #pragma unroll
    for (int r = 0; r < 8; ++r) acc[r] += dot4f(a4[(size_t)r*(K/4) + i], wv);
  }
  float bj = bias[j];
  #pragma unroll
  for (int r = 0; r < 8; ++r){
    float v;
    if (ACT == 2) v = acc[r] * (1.0f/3.0f) + bj;
    else          v = acc[r] + bj;
    if (ACT == 1) v = v / (1.0f + __expf(-v));
    int o = (bg*8 + r) * ncols + j;
    if (RES) v += res[o];
    out[o] = v;
  }
}

// -------- qproj[b,h,d] = sum_e qh[b,h*64+e] * Wk[h*64+e, d];  QW = qproj * sn_w[d] * scale --------
__global__ __launch_bounds__(256) void k_qproj(const float* __restrict__ qh,
    const float* __restrict__ Wk, const float* __restrict__ snw,
    float* __restrict__ qproj, float* __restrict__ QW){
  int tid = blockIdx.x * 256 + threadIdx.x;
  if (tid >= NB * NHEAD * DMODEL) return;
  int d = tid % DMODEL; int bh = tid / DMODEL;
  int h = bh % NHEAD;   int b = bh / NHEAD;
  const float* qrow = qh + (size_t)b * DMODEL + h * DHEAD;
  const float* wcol = Wk + (size_t)h * DHEAD * DMODEL + d;
  float acc = 0.0f;
  #pragma unroll 8
  for (int e = 0; e < DHEAD; ++e) acc = fmaf(qrow[e], wcol[(size_t)e * DMODEL], acc);
  qproj[tid] = acc;
  QW[tid] = acc * snw[d] * 0.125f;   // scale = 1/sqrt(64)
}

// -------- per (b,h): SQW = sum_d QW ; SC = scale*( sum_d qproj*sn_b + sum_e qh*bk ) --------
__global__ __launch_bounds__(256) void k_qred(const float* __restrict__ QW,
    const float* __restrict__ qproj, const float* __restrict__ qh,
    const float* __restrict__ snb, const float* __restrict__ bk,
    float* __restrict__ SQW, float* __restrict__ SC){
  int wid = (blockIdx.x * 256 + threadIdx.x) >> 6;
  int lane = threadIdx.x & 63;
  if (wid >= NB * NHEAD) return;
  int b = wid / NHEAD, h = wid % NHEAD;
  const float* qw = QW + (size_t)wid * DMODEL;
  const float* qp = qproj + (size_t)wid * DMODEL;
  float s1 = 0, s2 = 0;
  for (int i = lane; i < DMODEL; i += 64){ s1 += qw[i]; s2 = fmaf(qp[i], snb[i], s2); }
  float s3 = qh[(size_t)b * DMODEL + h * DHEAD + lane] * bk[h * DHEAD + lane];
  s1 = wsum(s1); s2 = wsum(s2); s3 = wsum(s3);
  if (lane == 0){ SQW[wid] = s1; SC[wid] = 0.125f * (s2 + s3); }
}

// -------- pass A: stream raw sequence rows; per row: stats + 12 head dots -> scores --------
__global__ __launch_bounds__(256, 2) void k_passA(const float* __restrict__ seq,
    const int* __restrict__ lens, const float* __restrict__ QW,
    const float* __restrict__ SQW, const float* __restrict__ SC,
    float* __restrict__ mbuf, float* __restrict__ rbuf, float* __restrict__ scores){
  int wg = blockIdx.x;               // (n*NB+b)*8 + chunk
  int chunk = wg & 7; int nb = wg >> 3;
  int wid = threadIdx.x >> 6; int lane = threadIdx.x & 63;
  int len = lens[nb];
  int b = nb % NB;
  int s0 = chunk * 64 + wid * 16;
  if (s0 >= len) return;
  int send = s0 + 16 < len ? s0 + 16 : len;
  const float4* qwb = (const float4*)(QW + (size_t)b * NHEAD * DMODEL);
  float4 qreg[NHEAD][3];
  #pragma unroll
  for (int h = 0; h < NHEAD; ++h){
    #pragma unroll
    for (int g = 0; g < 3; ++g) qreg[h][g] = qwb[h * (DMODEL/4) + g * 64 + lane];
  }
  float sqv[NHEAD], scv[NHEAD];
  #pragma unroll
  for (int h = 0; h < NHEAD; ++h){ sqv[h] = SQW[b*NHEAD + h]; scv[h] = SC[b*NHEAD + h]; }
  for (int s = s0; s < send; ++s){
    const float4* xr = (const float4*)(seq + ((size_t)nb * SEQLEN + s) * DMODEL);
    float4 x0 = xr[lane], x1 = xr[64 + lane], x2 = xr[128 + lane];
    float sm = x0.x+x0.y+x0.z+x0.w + x1.x+x1.y+x1.z+x1.w + x2.x+x2.y+x2.z+x2.w;
    float qq = dot4f(x0,x0) + dot4f(x1,x1) + dot4f(x2,x2);
    float dt[NHEAD];
    #pragma unroll
    for (int h = 0; h < NHEAD; ++h)
      dt[h] = dot4f(qreg[h][0],x0) + dot4f(qreg[h][1],x1) + dot4f(qreg[h][2],x2);
    sm = wsum(sm); qq = wsum(qq);
    #pragma unroll
    for (int h = 0; h < NHEAD; ++h) dt[h] = wsum(dt[h]);
    float m = sm * (1.0f/DMODEL);
    float var = qq * (1.0f/DMODEL) - m * m;
    float r = rsqrtf(var + 1e-5f);
    if (lane == 0){
      mbuf[(size_t)nb*SEQLEN + s] = m;
      rbuf[(size_t)nb*SEQLEN + s] = r;
      #pragma unroll
      for (int h = 0; h < NHEAD; ++h)
        scores[((size_t)nb*NHEAD + h)*SEQLEN + s] = r * (dt[h] - m * sqv[h]) + scv[h];
    }
  }
}

// -------- softmax per (n,b,h) row; writes aw = attn*rstd in place, c = sum attn*rstd*m --------
__global__ __launch_bounds__(256) void k_softmax(float* __restrict__ scores,
    const int* __restrict__ lens, const float* __restrict__ mbuf,
    const float* __restrict__ rbuf, float* __restrict__ cbuf){
  int row = (blockIdx.x * 256 + threadIdx.x) >> 6;
  int lane = threadIdx.x & 63;
  if (row >= NBROWS * NHEAD) return;
  int nb = row / NHEAD;
  int len = lens[nb];
  float* sp = scores + (size_t)row * SEQLEN;
  float v[8];
  float mx = -3.0e38f;
  #pragma unroll
  for (int i = 0; i < 8; ++i){
    int s = i*64 + lane;
    v[i] = sp[s];
    if (s < len) mx = fmaxf(mx, v[i]);
  }
  mx = wmaxf(mx);
  float sum = 0;
  #pragma unroll
  for (int i = 0; i < 8; ++i){
    int s = i*64 + lane;
    float e = (s < len) ? __expf(v[i] - mx) : 0.0f;
    v[i] = e; sum += e;
  }
  sum = wsum(sum);
  float inv = 1.0f / sum;
  float c = 0;
  #pragma unroll
  for (int i = 0; i < 8; ++i){
    int s = i*64 + lane;
    float r = (s < len) ? rbuf[(size_t)nb*SEQLEN + s] : 0.0f;
    float m = (s < len) ? mbuf[(size_t)nb*SEQLEN + s] : 0.0f;
    float a = v[i] * inv * r;
    sp[s] = a;
    c = fmaf(a, m, c);
  }
  c = wsum(c);
  if (lane == 0) cbuf[row] = c;
}

// -------- pass B: weighted sums of raw rows per head; partials per (nb, chunk) --------
__global__ __launch_bounds__(256, 2) void k_passB(const float* __restrict__ seq,
    const int* __restrict__ lens, const float* __restrict__ aw, float* __restrict__ P){
  int wg = blockIdx.x; int ch = wg & 3; int nb = wg >> 2;
  int wid = threadIdx.x >> 6; int lane = threadIdx.x & 63;
  int len = lens[nb];
  float4 acc[NHEAD][3];
  #pragma unroll
  for (int h = 0; h < NHEAD; ++h)
    #pragma unroll
    for (int g = 0; g < 3; ++g) acc[h][g] = make_float4(0,0,0,0);
  int s0 = ch * 128 + wid * 32;
  int send = s0 + 32 < len ? s0 + 32 : len;
  for (int s = s0; s < send; ++s){
    const float4* xr = (const float4*)(seq + ((size_t)nb * SEQLEN + s) * DMODEL);
    float4 x0 = xr[lane], x1 = xr[64 + lane], x2 = xr[128 + lane];
    #pragma unroll
    for (int h = 0; h < NHEAD; ++h){
      float a = aw[((size_t)nb*NHEAD + h)*SEQLEN + s];
      acc[h][0].x = fmaf(a, x0.x, acc[h][0].x);
      acc[h][0].y = fmaf(a, x0.y, acc[h][0].y);
      acc[h][0].z = fmaf(a, x0.z, acc[h][0].z);
      acc[h][0].w = fmaf(a, x0.w, acc[h][0].w);
      acc[h][1].x = fmaf(a, x1.x, acc[h][1].x);
      acc[h][1].y = fmaf(a, x1.y, acc[h][1].y);
      acc[h][1].z = fmaf(a, x1.z, acc[h][1].z);
      acc[h][1].w = fmaf(a, x1.w, acc[h][1].w);
      acc[h][2].x = fmaf(a, x2.x, acc[h][2].x);
      acc[h][2].y = fmaf(a, x2.y, acc[h][2].y);
      acc[h][2].z = fmaf(a, x2.z, acc[h][2].z);
      acc[h][2].w = fmaf(a, x2.w, acc[h][2].w);
    }
  }
  __shared__ float4 red[NHEAD * 192];   // 36 KB, layout = [h][768] floats
  for (int w = 0; w < 4; ++w){
    if (wid == w){
      #pragma unroll
      for (int h = 0; h < NHEAD; ++h)
        #pragma unroll
        for (int g = 0; g < 3; ++g){
          int idx = h*192 + g*64 + lane;
          if (w == 0) red[idx] = acc[h][g];
          else {
            float4 t = red[idx];
            t.x += acc[h][g].x; t.y += acc[h][g].y; t.z += acc[h][g].z; t.w += acc[h][g].w;
            red[idx] = t;
          }
        }
    }
    __syncthreads();
  }
  float4* Pout = (float4*)(P + ((size_t)nb*4 + ch) * NHEAD * DMODEL);
  for (int i = threadIdx.x; i < NHEAD*192; i += 256) Pout[i] = red[i];
}

// -------- reduce chunk partials + apply LN affine: wctx = (sum_ch P - c)*sn_w + sn_b --------
__global__ __launch_bounds__(256) void k_wctx(const float* __restrict__ P,
    const float* __restrict__ cbuf, const float* __restrict__ snw,
    const float* __restrict__ snb, float* __restrict__ wctx){
  int tid = blockIdx.x * 256 + threadIdx.x;
  if (tid >= NBROWS * NHEAD * DMODEL) return;
  int d = tid % DMODEL;
  int nbh = tid / DMODEL;
  int nb = nbh / NHEAD; int h = nbh % NHEAD;
  size_t base = (((size_t)nb*4) * NHEAD + h) * DMODEL + d;
  const size_t st = (size_t)NHEAD * DMODEL;
  float v = P[base] + P[base + st] + P[base + 2*st] + P[base + 3*st];
  wctx[tid] = (v - cbuf[nbh]) * snw[d] + snb[d];
}

// -------- ctxsum[b,he] = sum_n ( sum_d wctx[n,b,h,d]*Wv[he,d] ) + 3*bv[he] --------
__global__ __launch_bounds__(256) void k_ctxv(const float* __restrict__ wctx,
    const float* __restrict__ Wv, const float* __restrict__ bv, float* __restrict__ ctxsum){
  int tid = blockIdx.x * 256 + threadIdx.x;
  if (tid >= 8 * DMODEL) return;
  int bg = tid / DMODEL; int he = tid - bg * DMODEL; int h = he >> 6;
  const float4* w4 = (const float4*)(Wv + (size_t)he * DMODEL);
  float acc[8][3] = {};
  for (int i = 0; i < DMODEL/4; ++i){
    float4 wv = w4[i];
    #pragma unroll
    for (int n = 0; n < 3; ++n){
      #pragma unroll
      for (int r = 0; r < 8; ++r){
        const float4* c4 = (const float4*)(wctx + ((((size_t)n*NB + bg*8 + r)*NHEAD) + h) * DMODEL);
        acc[r][n] += dot4f(c4[i], wv);
      }
    }
  }
  float bvv = 3.0f * bv[he];
  #pragma unroll
  for (int r = 0; r < 8; ++r)
    ctxsum[(size_t)(bg*8 + r) * DMODEL + he] = acc[r][0] + acc[r][1] + acc[r][2] + bvv;
}

// -------- gate + residual: out = ctx + sigmoid([ctx,sctx]@Wg^T + gb) * sctx --------
__global__ __launch_bounds__(256) void k_gate(const float* __restrict__ ctx,
    const float* __restrict__ sctx, const float* __restrict__ Wg,
    const float* __restrict__ gb, float* __restrict__ out){
  int tid = blockIdx.x * 256 + threadIdx.x;
  if (tid >= 8 * DMODEL) return;
  int bg = tid / DMODEL; int j = tid - bg * DMODEL;
  const float4* w1 = (const float4*)(Wg + (size_t)j * 2 * DMODEL);
  const float4* w2 = w1 + DMODEL/4;
  float a1[8] = {}, a2[8] = {};
  for (int i = 0; i < DMODEL/4; ++i){
    float4 u = w1[i], v = w2[i];
    #pragma unroll
    for (int r = 0; r < 8; ++r){
      const float4* c4 = (const float4*)(ctx + (size_t)(bg*8 + r) * DMODEL);
      const float4* s4 = (const float4*)(sctx + (size_t)(bg*8 + r) * DMODEL);
      a1[r] += dot4f(c4[i], u);
      a2[r] += dot4f(s4[i], v);
    }
  }
  float bj = gb[j];
  #pragma unroll
  for (int r = 0; r < 8; ++r){
    int o = (bg*8 + r) * DMODEL + j;
    float g = 1.0f / (1.0f + __expf(-(a1[r] + a2[r] + bj)));
    out[o] = ctx[o] + g * sctx[o];
  }
}

// -------- classifier final dot: out[b] = sum_j h2[b,j]*w2[j] + b2 --------
__global__ __launch_bounds__(256) void k_cls2(const float* __restrict__ h2,
    const float* __restrict__ w2, const float* __restrict__ b2, float* __restrict__ out){
  int b = blockIdx.x; int t = threadIdx.x;
  float acc = 0;
  for (int j = t; j < FFNH; j += 256) acc = fmaf(h2[(size_t)b*FFNH + j], w2[j], acc);
  acc = wsum(acc);
  __shared__ float sh[4];
  if ((t & 63) == 0) sh[t >> 6] = acc;
  __syncthreads();
  if (t == 0) out[b] = sh[0] + sh[1] + sh[2] + sh[3] + b2[0];
}

extern "C" void kernel_launch(void* const* d_in, const int* in_sizes, int n_in,
                              void* d_out, int out_size, void* d_ws, size_t ws_size,
                              hipStream_t stream){
  const float* in_ctx = (const float*)d_in[0];
  const float* seq    = (const float*)d_in[1];
  const int*   lens   = (const int*)d_in[2];
  const float* qn_w   = (const float*)d_in[3];
  const float* qn_b   = (const float*)d_in[4];
  const float* sn_w   = (const float*)d_in[5];
  const float* sn_b   = (const float*)d_in[6];
  const float* in_w   = (const float*)d_in[7];
  const float* in_b   = (const float*)d_in[8];
  const float* out_w  = (const float*)d_in[9];
  const float* out_b  = (const float*)d_in[10];
  const float* gate_w = (const float*)d_in[11];
  const float* gate_b = (const float*)d_in[12];
  const float* fln_w  = (const float*)d_in[13];
  const float* fln_b  = (const float*)d_in[14];
  const float* fw1    = (const float*)d_in[15];
  const float* fb1    = (const float*)d_in[16];
  const float* fw2    = (const float*)d_in[17];
  const float* fb2    = (const float*)d_in[18];
  const float* on_w   = (const float*)d_in[19];
  const float* on_b   = (const float*)d_in[20];
  const float* cl_w   = (const float*)d_in[21];
  const float* cl_b   = (const float*)d_in[22];
  const float* cw1    = (const float*)d_in[23];
  const float* cb1    = (const float*)d_in[24];
  const float* cw2    = (const float*)d_in[25];
  const float* cb2    = (const float*)d_in[26];

  float* wsf = (float*)d_ws;
  size_t off = 0;
  auto alloc = [&](size_t n){ float* p = wsf + off; off += n; return p; };
  float* c0     = alloc((size_t)NB*DMODEL);
  float* c1     = alloc((size_t)NB*DMODEL);
  float* cmid   = alloc((size_t)NB*DMODEL);
  float* mbuf   = alloc((size_t)NBROWS*SEQLEN);
  float* rbuf   = alloc((size_t)NBROWS*SEQLEN);
  float* scores = alloc((size_t)NBROWS*NHEAD*SEQLEN);
  float* cbuf   = alloc((size_t)NBROWS*NHEAD);
  float* qln    = alloc((size_t)NB*DMODEL);
  float* qh     = alloc((size_t)NB*DMODEL);
  float* qproj  = alloc((size_t)NB*NHEAD*DMODEL);
  float* QW     = alloc((size_t)NB*NHEAD*DMODEL);
  float* SQWb   = alloc((size_t)NB*NHEAD);
  float* SCb    = alloc((size_t)NB*NHEAD);
  float* Pbuf   = alloc((size_t)NBROWS*4*NHEAD*DMODEL);
  float* wctx   = alloc((size_t)NBROWS*NHEAD*DMODEL);
  float* ctxsum = alloc((size_t)NB*DMODEL);
  float* sctx   = alloc((size_t)NB*DMODEL);
  float* h0     = alloc((size_t)NB*DMODEL);
  float* h1     = alloc((size_t)NB*FFNH);
  (void)ws_size; (void)in_sizes; (void)n_in; (void)out_size;

  hipMemcpyAsync(c0, in_ctx, (size_t)NB*DMODEL*sizeof(float), hipMemcpyDeviceToDevice, stream);
  float* cur = c0; float* nxt = c1;

  for (int l = 0; l < NBLK; ++l){
    const float* Wq = in_w + (size_t)l * 3 * DMODEL * DMODEL;
    const float* Wk = Wq + (size_t)DMODEL * DMODEL;
    const float* Wv = Wq + (size_t)2 * DMODEL * DMODEL;
    const float* bq = in_b + (size_t)l * 3 * DMODEL;
    const float* bk = bq + DMODEL;
    const float* bv = bq + 2 * DMODEL;

    k_ln<<<16, 256, 0, stream>>>(cur, qn_w + l*DMODEL, qn_b + l*DMODEL, qln, NB);
    k_gemmT<DMODEL,0,false><<<24, 256, 0, stream>>>(qln, Wq, bq, nullptr, qh, DMODEL);
    k_qproj<<<2304, 256, 0, stream>>>(qh, Wk, sn_w + l*DMODEL, qproj, QW);
    k_qred<<<192, 256, 0, stream>>>(QW, qproj, qh, sn_b + l*DMODEL, bk, SQWb, SCb);
    k_passA<<<NBROWS*8, 256, 0, stream>>>(seq, lens, QW, SQWb, SCb, mbuf, rbuf, scores);
    k_softmax<<<(NBROWS*NHEAD)/4, 256, 0, stream>>>(scores, lens, mbuf, rbuf, cbuf);
    k_passB<<<NBROWS*4, 256, 0, stream>>>(seq, lens, scores, Pbuf);
    k_wctx<<<(NBROWS*NHEAD*DMODEL + 255)/256, 256, 0, stream>>>(Pbuf, cbuf, sn_w + l*DMODEL, sn_b + l*DMODEL, wctx);
    k_ctxv<<<24, 256, 0, stream>>>(wctx, Wv, bv, ctxsum);
    k_gemmT<DMODEL,2,false><<<24, 256, 0, stream>>>(ctxsum, out_w + (size_t)l*DMODEL*DMODEL, out_b + l*DMODEL, nullptr, sctx, DMODEL);
    k_gate<<<24, 256, 0, stream>>>(cur, sctx, gate_w + (size_t)l*DMODEL*2*DMODEL, gate_b + l*DMODEL, cmid);
    k_ln<<<16, 256, 0, stream>>>(cmid, fln_w + l*DMODEL, fln_b + l*DMODEL, h0, NB);
    k_gemmT<DMODEL,1,false><<<96, 256, 0, stream>>>(h0, fw1 + (size_t)l*FFNH*DMODEL, fb1 + l*FFNH, nullptr, h1, FFNH);
    k_gemmT<FFNH,0,true><<<24, 256, 0, stream>>>(h1, fw2 + (size_t)l*DMODEL*FFNH, fb2 + l*DMODEL, cmid, nxt, DMODEL);
    float* t = cur; cur = nxt; nxt = t;
  }

  k_ln<<<16, 256, 0, stream>>>(cur, on_w, on_b, qln, NB);
  k_ln<<<16, 256, 0, stream>>>(qln, cl_w, cl_b, h0, NB);
  k_gemmT<DMODEL,1,false><<<96, 256, 0, stream>>>(h0, cw1, cb1, nullptr, h1, FFNH);
  k_cls2<<<64, 256, 0, stream>>>(h1, cw2, cb2, (float*)d_out);
}

// Round 2
// 717.843 us; speedup vs baseline: 3.6434x; 3.6434x over previous
//
#include <hip/hip_runtime.h>
#include <hip/hip_bf16.h>
#include <cstdint>

#define DMODEL 768
#define NB 64        // batch
#define NHEAD 12
#define DHEAD 64
#define SEQLEN 512
#define NDOM 3
#define NBLK 2
#define FFNH 3072
#define NBROWS (NDOM*NB)   // 192

__device__ __forceinline__ float wsum64(float v){
  #pragma unroll
  for (int o = 32; o; o >>= 1) v += __shfl_xor(v, o, 64);
  return v;
}
__device__ __forceinline__ float wmaxf(float v){
  #pragma unroll
  for (int o = 32; o; o >>= 1) v = fmaxf(v, __shfl_xor(v, o, 64));
  return v;
}
__device__ __forceinline__ float dot4f(float4 a, float4 b){
  return fmaf(a.x, b.x, fmaf(a.y, b.y, fmaf(a.z, b.z, a.w * b.w)));
}

// -------- LayerNorm: one wave per row of [rows, 768] --------
__global__ __launch_bounds__(256) void k_ln(const float* __restrict__ in,
    const float* __restrict__ w, const float* __restrict__ b,
    float* __restrict__ out, int rows){
  int gw = (blockIdx.x * 256 + threadIdx.x) >> 6;
  int lane = threadIdx.x & 63;
  if (gw >= rows) return;
  const float4* x4 = (const float4*)(in + (size_t)gw * DMODEL);
  float4 v0 = x4[lane], v1 = x4[64 + lane], v2 = x4[128 + lane];
  float s = v0.x+v0.y+v0.z+v0.w + v1.x+v1.y+v1.z+v1.w + v2.x+v2.y+v2.z+v2.w;
  float q = dot4f(v0,v0) + dot4f(v1,v1) + dot4f(v2,v2);
  s = wsum64(s); q = wsum64(q);
  float m = s * (1.0f / DMODEL);
  float var = q * (1.0f / DMODEL) - m * m;
  float r = rsqrtf(var + 1e-5f);
  const float4* w4 = (const float4*)w;
  const float4* b4 = (const float4*)b;
  float4* o4 = (float4*)(out + (size_t)gw * DMODEL);
  float4 vv[3] = {v0, v1, v2};
  #pragma unroll
  for (int seg = 0; seg < 3; ++seg){
    float4 ww = w4[seg*64 + lane], bb = b4[seg*64 + lane], x = vv[seg], o;
    o.x = (x.x - m) * r * ww.x + bb.x;
    o.y = (x.y - m) * r * ww.y + bb.y;
    o.z = (x.z - m) * r * ww.z + bb.z;
    o.w = (x.w - m) * r * ww.w + bb.w;
    o4[seg*64 + lane] = o;
  }
}

// -------- wave-per-column GEMM: out[64,NC] = act(A[64,K] @ W[NC,K]^T + bias) --------
// Wave = (bg, j): 8 lane-groups of 8, group g owns batch row bg*8+g, lanes split K.
// Weight row j is read CONTIGUOUSLY (128B per group per iter). 3-step shfl reduce.
// ACT: 0 none, 1 silu, 2 (acc/3 + bias) ; RES: add residual res[o]
template<int K, int NC, int ACT, bool RES>
__global__ __launch_bounds__(256) void k_gemmW(const float* __restrict__ A,
    const float* __restrict__ W, const float* __restrict__ bias,
    const float* __restrict__ res, float* __restrict__ out){
  int gw = (blockIdx.x * 256 + threadIdx.x) >> 6;   // global wave id, 8*NC total
  int lane = threadIdx.x & 63;
  int sl = lane & 7, g = lane >> 3;
  int bg = gw / NC; int j = gw - bg * NC;
  const float4* w4 = (const float4*)(W + (size_t)j * K);
  const float4* a4 = (const float4*)(A + (size_t)(bg*8 + g) * K);
  float acc = 0.0f;
  #pragma unroll 8
  for (int i = 0; i < K/32; ++i)
    acc += dot4f(a4[i*8 + sl], w4[i*8 + sl]);
  acc += __shfl_xor(acc, 1, 64);
  acc += __shfl_xor(acc, 2, 64);
  acc += __shfl_xor(acc, 4, 64);
  if (sl == 0){
    float bj = bias[j];
    float v = (ACT == 2) ? acc * (1.0f/3.0f) + bj : acc + bj;
    if (ACT == 1) v = v / (1.0f + __expf(-v));
    size_t o = (size_t)(bg*8 + g) * NC + j;
    if (RES) v += res[o];
    out[o] = v;
  }
}

// -------- qproj[b,h,d] = sum_e qh[b,h*64+e] * Wk[h*64+e, d];  QW = qproj * sn_w[d] * scale --------
__global__ __launch_bounds__(256) void k_qproj(const float* __restrict__ qh,
    const float* __restrict__ Wk, const float* __restrict__ snw,
    float* __restrict__ qproj, float* __restrict__ QW){
  int tid = blockIdx.x * 256 + threadIdx.x;
  if (tid >= NB * NHEAD * DMODEL) return;
  int d = tid % DMODEL; int bh = tid / DMODEL;
  int h = bh % NHEAD;   int b = bh / NHEAD;
  const float* qrow = qh + (size_t)b * DMODEL + h * DHEAD;
  const float* wcol = Wk + (size_t)h * DHEAD * DMODEL + d;
  float acc = 0.0f;
  #pragma unroll 8
  for (int e = 0; e < DHEAD; ++e) acc = fmaf(qrow[e], wcol[(size_t)e * DMODEL], acc);
  qproj[tid] = acc;
  QW[tid] = acc * snw[d] * 0.125f;   // scale = 1/sqrt(64)
}

// -------- per (b,h): SQW = sum_d QW ; SC = scale*( sum_d qproj*sn_b + sum_e qh*bk ) --------
__global__ __launch_bounds__(256) void k_qred(const float* __restrict__ QW,
    const float* __restrict__ qproj, const float* __restrict__ qh,
    const float* __restrict__ snb, const float* __restrict__ bk,
    float* __restrict__ SQW, float* __restrict__ SC){
  int wid = (blockIdx.x * 256 + threadIdx.x) >> 6;
  int lane = threadIdx.x & 63;
  if (wid >= NB * NHEAD) return;
  int b = wid / NHEAD, h = wid % NHEAD;
  const float* qw = QW + (size_t)wid * DMODEL;
  const float* qp = qproj + (size_t)wid * DMODEL;
  float s1 = 0, s2 = 0;
  for (int i = lane; i < DMODEL; i += 64){ s1 += qw[i]; s2 = fmaf(qp[i], snb[i], s2); }
  float s3 = qh[(size_t)b * DMODEL + h * DHEAD + lane] * bk[h * DHEAD + lane];
  s1 = wsum64(s1); s2 = wsum64(s2); s3 = wsum64(s3);
  if (lane == 0){ SQW[wid] = s1; SC[wid] = 0.125f * (s2 + s3); }
}

// -------- pass A: stream raw sequence rows; per row: stats + 12 head dots -> scores --------
__global__ __launch_bounds__(256, 2) void k_passA(const float* __restrict__ seq,
    const int* __restrict__ lens, const float* __restrict__ QW,
    const float* __restrict__ SQW, const float* __restrict__ SC,
    float* __restrict__ mbuf, float* __restrict__ rbuf, float* __restrict__ scores){
  int wg = blockIdx.x;               // (n*NB+b)*8 + chunk
  int chunk = wg & 7; int nb = wg >> 3;
  int wid = threadIdx.x >> 6; int lane = threadIdx.x & 63;
  int len = lens[nb];
  int b = nb % NB;
  int s0 = chunk * 64 + wid * 16;
  if (s0 >= len) return;
  int send = s0 + 16 < len ? s0 + 16 : len;
  const float4* qwb = (const float4*)(QW + (size_t)b * NHEAD * DMODEL);
  float4 qreg[NHEAD][3];
  #pragma unroll
  for (int h = 0; h < NHEAD; ++h){
    #pragma unroll
    for (int g = 0; g < 3; ++g) qreg[h][g] = qwb[h * (DMODEL/4) + g * 64 + lane];
  }
  float sqv[NHEAD], scv[NHEAD];
  #pragma unroll
  for (int h = 0; h < NHEAD; ++h){ sqv[h] = SQW[b*NHEAD + h]; scv[h] = SC[b*NHEAD + h]; }
  for (int s = s0; s < send; ++s){
    const float4* xr = (const float4*)(seq + ((size_t)nb * SEQLEN + s) * DMODEL);
    float4 x0 = xr[lane], x1 = xr[64 + lane], x2 = xr[128 + lane];
    float sm = x0.x+x0.y+x0.z+x0.w + x1.x+x1.y+x1.z+x1.w + x2.x+x2.y+x2.z+x2.w;
    float qq = dot4f(x0,x0) + dot4f(x1,x1) + dot4f(x2,x2);
    float dt[NHEAD];
    #pragma unroll
    for (int h = 0; h < NHEAD; ++h)
      dt[h] = dot4f(qreg[h][0],x0) + dot4f(qreg[h][1],x1) + dot4f(qreg[h][2],x2);
    sm = wsum64(sm); qq = wsum64(qq);
    #pragma unroll
    for (int h = 0; h < NHEAD; ++h) dt[h] = wsum64(dt[h]);
    float m = sm * (1.0f/DMODEL);
    float var = qq * (1.0f/DMODEL) - m * m;
    float r = rsqrtf(var + 1e-5f);
    if (lane == 0){
      mbuf[(size_t)nb*SEQLEN + s] = m;
      rbuf[(size_t)nb*SEQLEN + s] = r;
      #pragma unroll
      for (int h = 0; h < NHEAD; ++h)
        scores[((size_t)nb*NHEAD + h)*SEQLEN + s] = r * (dt[h] - m * sqv[h]) + scv[h];
    }
  }
}

// -------- softmax per (n,b,h) row; writes aw = attn*rstd in place, c = sum attn*rstd*m --------
__global__ __launch_bounds__(256) void k_softmax(float* __restrict__ scores,
    const int* __restrict__ lens, const float* __restrict__ mbuf,
    const float* __restrict__ rbuf, float* __restrict__ cbuf){
  int row = (blockIdx.x * 256 + threadIdx.x) >> 6;
  int lane = threadIdx.x & 63;
  if (row >= NBROWS * NHEAD) return;
  int nb = row / NHEAD;
  int len = lens[nb];
  float* sp = scores + (size_t)row * SEQLEN;
  float v[8];
  float mx = -3.0e38f;
  #pragma unroll
  for (int i = 0; i < 8; ++i){
    int s = i*64 + lane;
    v[i] = sp[s];
    if (s < len) mx = fmaxf(mx, v[i]);
  }
  mx = wmaxf(mx);
  float sum = 0;
  #pragma unroll
  for (int i = 0; i < 8; ++i){
    int s = i*64 + lane;
    float e = (s < len) ? __expf(v[i] - mx) : 0.0f;
    v[i] = e; sum += e;
  }
  sum = wsum64(sum);
  float inv = 1.0f / sum;
  float c = 0;
  #pragma unroll
  for (int i = 0; i < 8; ++i){
    int s = i*64 + lane;
    float r = (s < len) ? rbuf[(size_t)nb*SEQLEN + s] : 0.0f;
    float m = (s < len) ? mbuf[(size_t)nb*SEQLEN + s] : 0.0f;
    float a = v[i] * inv * r;
    sp[s] = a;
    c = fmaf(a, m, c);
  }
  c = wsum64(c);
  if (lane == 0) cbuf[row] = c;
}

// -------- pass B: weighted sums of raw rows per head; partials per (nb, chunk) --------
__global__ __launch_bounds__(256, 2) void k_passB(const float* __restrict__ seq,
    const int* __restrict__ lens, const float* __restrict__ aw, float* __restrict__ P){
  int wg = blockIdx.x; int ch = wg & 3; int nb = wg >> 2;
  int wid = threadIdx.x >> 6; int lane = threadIdx.x & 63;
  int len = lens[nb];
  float4 acc[NHEAD][3];
  #pragma unroll
  for (int h = 0; h < NHEAD; ++h)
    #pragma unroll
    for (int g = 0; g < 3; ++g) acc[h][g] = make_float4(0,0,0,0);
  int s0 = ch * 128 + wid * 32;
  int send = s0 + 32 < len ? s0 + 32 : len;
  for (int s = s0; s < send; ++s){
    const float4* xr = (const float4*)(seq + ((size_t)nb * SEQLEN + s) * DMODEL);
    float4 x0 = xr[lane], x1 = xr[64 + lane], x2 = xr[128 + lane];
    #pragma unroll
    for (int h = 0; h < NHEAD; ++h){
      float a = aw[((size_t)nb*NHEAD + h)*SEQLEN + s];
      acc[h][0].x = fmaf(a, x0.x, acc[h][0].x);
      acc[h][0].y = fmaf(a, x0.y, acc[h][0].y);
      acc[h][0].z = fmaf(a, x0.z, acc[h][0].z);
      acc[h][0].w = fmaf(a, x0.w, acc[h][0].w);
      acc[h][1].x = fmaf(a, x1.x, acc[h][1].x);
      acc[h][1].y = fmaf(a, x1.y, acc[h][1].y);
      acc[h][1].z = fmaf(a, x1.z, acc[h][1].z);
      acc[h][1].w = fmaf(a, x1.w, acc[h][1].w);
      acc[h][2].x = fmaf(a, x2.x, acc[h][2].x);
      acc[h][2].y = fmaf(a, x2.y, acc[h][2].y);
      acc[h][2].z = fmaf(a, x2.z, acc[h][2].z);
      acc[h][2].w = fmaf(a, x2.w, acc[h][2].w);
    }
  }
  __shared__ float4 red[NHEAD * 192];   // 36 KB, layout = [h][768] floats
  for (int w = 0; w < 4; ++w){
    if (wid == w){
      #pragma unroll
      for (int h = 0; h < NHEAD; ++h)
        #pragma unroll
        for (int g = 0; g < 3; ++g){
          int idx = h*192 + g*64 + lane;
          if (w == 0) red[idx] = acc[h][g];
          else {
            float4 t = red[idx];
            t.x += acc[h][g].x; t.y += acc[h][g].y; t.z += acc[h][g].z; t.w += acc[h][g].w;
            red[idx] = t;
          }
        }
    }
    __syncthreads();
  }
  float4* Pout = (float4*)(P + ((size_t)nb*4 + ch) * NHEAD * DMODEL);
  for (int i = threadIdx.x; i < NHEAD*192; i += 256) Pout[i] = red[i];
}

// -------- reduce chunk partials over ch AND n, apply LN affine:
// wsum[b,h,d] = (sum_{n,ch} P - sum_n c) * sn_w[d] + 3*sn_b[d] --------
__global__ __launch_bounds__(256) void k_wctx2(const float* __restrict__ P,
    const float* __restrict__ cbuf, const float* __restrict__ snw,
    const float* __restrict__ snb, float* __restrict__ wsum){
  int tid = blockIdx.x * 256 + threadIdx.x;
  if (tid >= NB * NHEAD * DMODEL) return;
  int d = tid % DMODEL;
  int t = tid / DMODEL;
  int h = t % NHEAD;
  int b = t / NHEAD;
  const size_t st = (size_t)NHEAD * DMODEL;
  float v = 0.0f, c = 0.0f;
  #pragma unroll
  for (int n = 0; n < NDOM; ++n){
    int nb = n*NB + b;
    size_t base = ((size_t)nb*4) * st + (size_t)h * DMODEL + d;
    v += P[base] + P[base + st] + P[base + 2*st] + P[base + 3*st];
    c += cbuf[nb*NHEAD + h];
  }
  wsum[tid] = (v - c) * snw[d] + 3.0f * snb[d];
}

// -------- ctxsum[b,he] = sum_d wsum[b,h,d]*Wv[he,d] + 3*bv[he]  (h = he>>6) --------
// same wave-per-column structure as k_gemmW
__global__ __launch_bounds__(256) void k_ctxv2(const float* __restrict__ wsum,
    const float* __restrict__ Wv, const float* __restrict__ bv, float* __restrict__ ctxsum){
  int gw = (blockIdx.x * 256 + threadIdx.x) >> 6;   // 8*768 waves
  int lane = threadIdx.x & 63;
  int sl = lane & 7, g = lane >> 3;
  int bg = gw / DMODEL; int he = gw - bg * DMODEL;
  int h = he >> 6;
  const float4* w4 = (const float4*)(Wv + (size_t)he * DMODEL);
  const float4* a4 = (const float4*)(wsum + ((size_t)(bg*8 + g) * NHEAD + h) * DMODEL);
  float acc = 0.0f;
  #pragma unroll 8
  for (int i = 0; i < DMODEL/32; ++i)
    acc += dot4f(a4[i*8 + sl], w4[i*8 + sl]);
  acc += __shfl_xor(acc, 1, 64);
  acc += __shfl_xor(acc, 2, 64);
  acc += __shfl_xor(acc, 4, 64);
  if (sl == 0)
    ctxsum[(size_t)(bg*8 + g) * DMODEL + he] = acc + 3.0f * bv[he];
}

// -------- gate + residual, wave-per-column: out = ctx + sigmoid([ctx,sctx]@Wg^T + gb) * sctx --------
__global__ __launch_bounds__(256) void k_gate2(const float* __restrict__ ctx,
    const float* __restrict__ sctx, const float* __restrict__ Wg,
    const float* __restrict__ gb, float* __restrict__ out){
  int gw = (blockIdx.x * 256 + threadIdx.x) >> 6;   // 8*768 waves
  int lane = threadIdx.x & 63;
  int sl = lane & 7, g = lane >> 3;
  int bg = gw / DMODEL; int j = gw - bg * DMODEL;
  int row = bg*8 + g;
  const float4* w1 = (const float4*)(Wg + (size_t)j * 2 * DMODEL);
  const float4* w2 = w1 + DMODEL/4;
  const float4* c4 = (const float4*)(ctx + (size_t)row * DMODEL);
  const float4* s4 = (const float4*)(sctx + (size_t)row * DMODEL);
  float acc = 0.0f;
  #pragma unroll 8
  for (int i = 0; i < DMODEL/32; ++i)
    acc += dot4f(c4[i*8 + sl], w1[i*8 + sl]) + dot4f(s4[i*8 + sl], w2[i*8 + sl]);
  acc += __shfl_xor(acc, 1, 64);
  acc += __shfl_xor(acc, 2, 64);
  acc += __shfl_xor(acc, 4, 64);
  if (sl == 0){
    size_t o = (size_t)row * DMODEL + j;
    float gt = 1.0f / (1.0f + __expf(-(acc + gb[j])));
    out[o] = ctx[o] + gt * sctx[o];
  }
}

// -------- classifier final dot: out[b] = sum_j h2[b,j]*w2[j] + b2 --------
__global__ __launch_bounds__(256) void k_cls2(const float* __restrict__ h2,
    const float* __restrict__ w2, const float* __restrict__ b2, float* __restrict__ out){
  int b = blockIdx.x; int t = threadIdx.x;
  float acc = 0;
  for (int j = t; j < FFNH; j += 256) acc = fmaf(h2[(size_t)b*FFNH + j], w2[j], acc);
  acc = wsum64(acc);
  __shared__ float sh[4];
  if ((t & 63) == 0) sh[t >> 6] = acc;
  __syncthreads();
  if (t == 0) out[b] = sh[0] + sh[1] + sh[2] + sh[3] + b2[0];
}

extern "C" void kernel_launch(void* const* d_in, const int* in_sizes, int n_in,
                              void* d_out, int out_size, void* d_ws, size_t ws_size,
                              hipStream_t stream){
  const float* in_ctx = (const float*)d_in[0];
  const float* seq    = (const float*)d_in[1];
  const int*   lens   = (const int*)d_in[2];
  const float* qn_w   = (const float*)d_in[3];
  const float* qn_b   = (const float*)d_in[4];
  const float* sn_w   = (const float*)d_in[5];
  const float* sn_b   = (const float*)d_in[6];
  const float* in_w   = (const float*)d_in[7];
  const float* in_b   = (const float*)d_in[8];
  const float* out_w  = (const float*)d_in[9];
  const float* out_b  = (const float*)d_in[10];
  const float* gate_w = (const float*)d_in[11];
  const float* gate_b = (const float*)d_in[12];
  const float* fln_w  = (const float*)d_in[13];
  const float* fln_b  = (const float*)d_in[14];
  const float* fw1    = (const float*)d_in[15];
  const float* fb1    = (const float*)d_in[16];
  const float* fw2    = (const float*)d_in[17];
  const float* fb2    = (const float*)d_in[18];
  const float* on_w   = (const float*)d_in[19];
  const float* on_b   = (const float*)d_in[20];
  const float* cl_w   = (const float*)d_in[21];
  const float* cl_b   = (const float*)d_in[22];
  const float* cw1    = (const float*)d_in[23];
  const float* cb1    = (const float*)d_in[24];
  const float* cw2    = (const float*)d_in[25];
  const float* cb2    = (const float*)d_in[26];

  float* wsf = (float*)d_ws;
  size_t off = 0;
  auto alloc = [&](size_t n){ float* p = wsf + off; off += n; return p; };
  float* c0     = alloc((size_t)NB*DMODEL);
  float* c1     = alloc((size_t)NB*DMODEL);
  float* cmid   = alloc((size_t)NB*DMODEL);
  float* mbuf   = alloc((size_t)NBROWS*SEQLEN);
  float* rbuf   = alloc((size_t)NBROWS*SEQLEN);
  float* scores = alloc((size_t)NBROWS*NHEAD*SEQLEN);
  float* cbuf   = alloc((size_t)NBROWS*NHEAD);
  float* qln    = alloc((size_t)NB*DMODEL);
  float* qh     = alloc((size_t)NB*DMODEL);
  float* qproj  = alloc((size_t)NB*NHEAD*DMODEL);
  float* QW     = alloc((size_t)NB*NHEAD*DMODEL);
  float* SQWb   = alloc((size_t)NB*NHEAD);
  float* SCb    = alloc((size_t)NB*NHEAD);
  float* Pbuf   = alloc((size_t)NBROWS*4*NHEAD*DMODEL);
  float* wsumb  = alloc((size_t)NB*NHEAD*DMODEL);
  float* ctxsum = alloc((size_t)NB*DMODEL);
  float* sctx   = alloc((size_t)NB*DMODEL);
  float* h0     = alloc((size_t)NB*DMODEL);
  float* h1     = alloc((size_t)NB*FFNH);
  (void)ws_size; (void)in_sizes; (void)n_in; (void)out_size;

  hipMemcpyAsync(c0, in_ctx, (size_t)NB*DMODEL*sizeof(float), hipMemcpyDeviceToDevice, stream);
  float* cur = c0; float* nxt = c1;

  for (int l = 0; l < NBLK; ++l){
    const float* Wq = in_w + (size_t)l * 3 * DMODEL * DMODEL;
    const float* Wk = Wq + (size_t)DMODEL * DMODEL;
    const float* Wv = Wq + (size_t)2 * DMODEL * DMODEL;
    const float* bq = in_b + (size_t)l * 3 * DMODEL;
    const float* bk = bq + DMODEL;
    const float* bv = bq + 2 * DMODEL;

    k_ln<<<16, 256, 0, stream>>>(cur, qn_w + l*DMODEL, qn_b + l*DMODEL, qln, NB);
    k_gemmW<DMODEL,DMODEL,0,false><<<2*DMODEL, 256, 0, stream>>>(qln, Wq, bq, nullptr, qh);
    k_qproj<<<2304, 256, 0, stream>>>(qh, Wk, sn_w + l*DMODEL, qproj, QW);
    k_qred<<<192, 256, 0, stream>>>(QW, qproj, qh, sn_b + l*DMODEL, bk, SQWb, SCb);
    k_passA<<<NBROWS*8, 256, 0, stream>>>(seq, lens, QW, SQWb, SCb, mbuf, rbuf, scores);
    k_softmax<<<(NBROWS*NHEAD)/4, 256, 0, stream>>>(scores, lens, mbuf, rbuf, cbuf);
    k_passB<<<NBROWS*4, 256, 0, stream>>>(seq, lens, scores, Pbuf);
    k_wctx2<<<(NB*NHEAD*DMODEL + 255)/256, 256, 0, stream>>>(Pbuf, cbuf, sn_w + l*DMODEL, sn_b + l*DMODEL, wsumb);
    k_ctxv2<<<2*DMODEL, 256, 0, stream>>>(wsumb, Wv, bv, ctxsum);
    k_gemmW<DMODEL,DMODEL,2,false><<<2*DMODEL, 256, 0, stream>>>(ctxsum, out_w + (size_t)l*DMODEL*DMODEL, out_b + l*DMODEL, nullptr, sctx);
    k_gate2<<<2*DMODEL, 256, 0, stream>>>(cur, sctx, gate_w + (size_t)l*DMODEL*2*DMODEL, gate_b + l*DMODEL, cmid);
    k_ln<<<16, 256, 0, stream>>>(cmid, fln_w + l*DMODEL, fln_b + l*DMODEL, h0, NB);
    k_gemmW<DMODEL,FFNH,1,false><<<2*FFNH, 256, 0, stream>>>(h0, fw1 + (size_t)l*FFNH*DMODEL, fb1 + l*FFNH, nullptr, h1);
    k_gemmW<FFNH,DMODEL,0,true><<<2*DMODEL, 256, 0, stream>>>(h1, fw2 + (size_t)l*DMODEL*FFNH, fb2 + l*DMODEL, cmid, nxt);
    float* t = cur; cur = nxt; nxt = t;
  }

  k_ln<<<16, 256, 0, stream>>>(cur, on_w, on_b, qln, NB);
  k_ln<<<16, 256, 0, stream>>>(qln, cl_w, cl_b, h0, NB);
  k_gemmW<DMODEL,FFNH,1,false><<<2*FFNH, 256, 0, stream>>>(h0, cw1, cb1, nullptr, h1);
  k_cls2<<<64, 256, 0, stream>>>(h1, cw2, cb2, (float*)d_out);
}

// Round 3
// 659.499 us; speedup vs baseline: 3.9657x; 1.0885x over previous
//
#include <hip/hip_runtime.h>
#include <hip/hip_bf16.h>
#include <cstdint>

#define DMODEL 768
#define NB 64        // batch
#define NHEAD 12
#define DHEAD 64
#define SEQLEN 512
#define NDOM 3
#define NBLK 2
#define FFNH 3072
#define NBROWS (NDOM*NB)   // 192
#define NCH 4              // row chunks per (n,b) in fused attention
#define ROWCH (SEQLEN/NCH) // 128

__device__ __forceinline__ float wsum64(float v){
  #pragma unroll
  for (int o = 32; o; o >>= 1) v += __shfl_xor(v, o, 64);
  return v;
}
__device__ __forceinline__ float dot4f(float4 a, float4 b){
  return fmaf(a.x, b.x, fmaf(a.y, b.y, fmaf(a.z, b.z, a.w * b.w)));
}

// -------- LayerNorm: one wave per row of [rows, 768] --------
__global__ __launch_bounds__(256) void k_ln(const float* __restrict__ in,
    const float* __restrict__ w, const float* __restrict__ b,
    float* __restrict__ out, int rows){
  int gw = (blockIdx.x * 256 + threadIdx.x) >> 6;
  int lane = threadIdx.x & 63;
  if (gw >= rows) return;
  const float4* x4 = (const float4*)(in + (size_t)gw * DMODEL);
  float4 v0 = x4[lane], v1 = x4[64 + lane], v2 = x4[128 + lane];
  float s = v0.x+v0.y+v0.z+v0.w + v1.x+v1.y+v1.z+v1.w + v2.x+v2.y+v2.z+v2.w;
  float q = dot4f(v0,v0) + dot4f(v1,v1) + dot4f(v2,v2);
  s = wsum64(s); q = wsum64(q);
  float m = s * (1.0f / DMODEL);
  float var = q * (1.0f / DMODEL) - m * m;
  float r = rsqrtf(var + 1e-5f);
  const float4* w4 = (const float4*)w;
  const float4* b4 = (const float4*)b;
  float4* o4 = (float4*)(out + (size_t)gw * DMODEL);
  float4 vv[3] = {v0, v1, v2};
  #pragma unroll
  for (int seg = 0; seg < 3; ++seg){
    float4 ww = w4[seg*64 + lane], bb = b4[seg*64 + lane], x = vv[seg], o;
    o.x = (x.x - m) * r * ww.x + bb.x;
    o.y = (x.y - m) * r * ww.y + bb.y;
    o.z = (x.z - m) * r * ww.z + bb.z;
    o.w = (x.w - m) * r * ww.w + bb.w;
    o4[seg*64 + lane] = o;
  }
}

// -------- wave-per-4-columns GEMM: out[64,NC] = act(A[64,K] @ W[NC,K]^T + bias) --------
// Wave = (bg, j0..j0+3): 8 lane-groups of 8, group g owns batch row bg*8+g, lanes split K.
// One A load amortized over JB=4 weight rows. float4 output store.
template<int K, int NC, int ACT, bool RES>
__global__ __launch_bounds__(256) void k_gemmW(const float* __restrict__ A,
    const float* __restrict__ W, const float* __restrict__ bias,
    const float* __restrict__ res, float* __restrict__ out){
  const int NJ = NC / 4;
  int gw = (blockIdx.x * 256 + threadIdx.x) >> 6;   // 8*NJ waves
  int lane = threadIdx.x & 63;
  int sl = lane & 7, g = lane >> 3;
  int bg = gw / NJ; int j0 = (gw - bg * NJ) * 4;
  const float4* a4 = (const float4*)(A + (size_t)(bg*8 + g) * K);
  const float4* w0 = (const float4*)(W + (size_t)(j0+0) * K);
  const float4* w1 = (const float4*)(W + (size_t)(j0+1) * K);
  const float4* w2 = (const float4*)(W + (size_t)(j0+2) * K);
  const float4* w3 = (const float4*)(W + (size_t)(j0+3) * K);
  float acc0 = 0, acc1 = 0, acc2 = 0, acc3 = 0;
  #pragma unroll 4
  for (int i = 0; i < K/32; ++i){
    float4 av = a4[i*8 + sl];
    acc0 += dot4f(av, w0[i*8 + sl]);
    acc1 += dot4f(av, w1[i*8 + sl]);
    acc2 += dot4f(av, w2[i*8 + sl]);
    acc3 += dot4f(av, w3[i*8 + sl]);
  }
  #pragma unroll
  for (int o = 1; o <= 4; o <<= 1){
    acc0 += __shfl_xor(acc0, o, 64);
    acc1 += __shfl_xor(acc1, o, 64);
    acc2 += __shfl_xor(acc2, o, 64);
    acc3 += __shfl_xor(acc3, o, 64);
  }
  if (sl == 0){
    int row = bg*8 + g;
    float4 bj = *(const float4*)(bias + j0);
    float a[4] = {acc0, acc1, acc2, acc3};
    float bb[4] = {bj.x, bj.y, bj.z, bj.w};
    float v[4];
    #pragma unroll
    for (int u = 0; u < 4; ++u){
      float t = (ACT == 2) ? a[u] * (1.0f/3.0f) + bb[u] : a[u] + bb[u];
      if (ACT == 1) t = t / (1.0f + __expf(-t));
      v[u] = t;
    }
    size_t o = (size_t)row * NC + j0;
    if (RES){
      float4 rr = *(const float4*)(res + o);
      v[0] += rr.x; v[1] += rr.y; v[2] += rr.z; v[3] += rr.w;
    }
    *(float4*)(out + o) = make_float4(v[0], v[1], v[2], v[3]);
  }
}

// -------- fused qproj + reductions: wave per (b,h) --------
// qp[d] = sum_e qh[b,h*64+e]*Wk[h*64+e,d]; QW = qp*snw*scale;
// SQW = sum_d QW; SC = scale*(sum_d qp*snb + sum_e qh*bk)
__global__ __launch_bounds__(256) void k_qpr(const float* __restrict__ qh,
    const float* __restrict__ Wk, const float* __restrict__ snw,
    const float* __restrict__ snb, const float* __restrict__ bk,
    float* __restrict__ QW, float* __restrict__ SQW, float* __restrict__ SC){
  int w = (blockIdx.x * 256 + threadIdx.x) >> 6;   // 768 waves
  int lane = threadIdx.x & 63;
  int b = w / NHEAD, h = w - b * NHEAD;
  const float* qrow = qh + (size_t)b * DMODEL + h * DHEAD;
  const float* wbase = Wk + (size_t)h * DHEAD * DMODEL;
  float qp[12] = {};
  for (int e = 0; e < DHEAD; ++e){
    float qv = qrow[e];
    const float* wr = wbase + (size_t)e * DMODEL;
    #pragma unroll
    for (int k = 0; k < 12; ++k) qp[k] = fmaf(qv, wr[k*64 + lane], qp[k]);
  }
  float s1 = 0, s2 = 0;
  float* qwout = QW + (size_t)w * DMODEL;
  #pragma unroll
  for (int k = 0; k < 12; ++k){
    int d = k*64 + lane;
    float q = qp[k];
    float qwv = q * snw[d] * 0.125f;
    qwout[d] = qwv;
    s1 += qwv;
    s2 = fmaf(q, snb[d], s2);
  }
  float s3 = qrow[lane] * bk[h*DHEAD + lane];
  s1 = wsum64(s1); s2 = wsum64(s2); s3 = wsum64(s3);
  if (lane == 0){ SQW[w] = s1; SC[w] = 0.125f * (s2 + s3); }
}

// -------- fused attention: stream seq rows ONCE, online softmax per head --------
// block = (nb, ch) chunk of 128 rows; 4 waves split 12 heads 3-each.
// Per row: LN stats + 3 head scores + online-softmax accumulate of raw row.
__global__ __launch_bounds__(256, 2) void k_attn(const float* __restrict__ seq,
    const int* __restrict__ lens, const float* __restrict__ QW,
    const float* __restrict__ SQW, const float* __restrict__ SC,
    float* __restrict__ Pacc, float* __restrict__ Pden,
    float* __restrict__ Pc, float* __restrict__ Pmx){
  int blk = blockIdx.x;              // nb*NCH + ch
  int ch = blk & (NCH-1); int nb = blk >> 2;
  int wid = threadIdx.x >> 6; int lane = threadIdx.x & 63;
  int b = nb % NB;
  int len = lens[nb];
  int s0 = ch * ROWCH;
  int h0 = wid * 3;
  size_t pb = (size_t)blk * NHEAD + h0;
  if (s0 >= len){
    #pragma unroll
    for (int j = 0; j < 3; ++j){
      float* pa = Pacc + (pb + j) * DMODEL;
      #pragma unroll
      for (int k = 0; k < 12; ++k) pa[k*64 + lane] = 0.0f;
      if (lane == 0){ Pden[pb+j] = 0.0f; Pc[pb+j] = 0.0f; Pmx[pb+j] = -3.0e38f; }
    }
    return;
  }
  int send = s0 + ROWCH < len ? s0 + ROWCH : len;
  const float4* qwb = (const float4*)(QW + ((size_t)b * NHEAD + h0) * DMODEL);
  float4 q0[3], q1[3], q2[3];
  #pragma unroll
  for (int j = 0; j < 3; ++j){
    q0[j] = qwb[j*(DMODEL/4) + lane];
    q1[j] = qwb[j*(DMODEL/4) + 64 + lane];
    q2[j] = qwb[j*(DMODEL/4) + 128 + lane];
  }
  float sqv[3], scv[3];
  #pragma unroll
  for (int j = 0; j < 3; ++j){ sqv[j] = SQW[b*NHEAD + h0 + j]; scv[j] = SC[b*NHEAD + h0 + j]; }
  float4 a0[3], a1[3], a2[3];
  #pragma unroll
  for (int j = 0; j < 3; ++j){
    a0[j] = make_float4(0,0,0,0); a1[j] = make_float4(0,0,0,0); a2[j] = make_float4(0,0,0,0);
  }
  float den[3] = {0,0,0}, cac[3] = {0,0,0}, mx[3] = {-3.0e38f,-3.0e38f,-3.0e38f};
  const float4* xr = (const float4*)(seq + ((size_t)nb * SEQLEN + s0) * DMODEL);
  float4 x0 = xr[lane], x1 = xr[64 + lane], x2 = xr[128 + lane];
  for (int s = s0; s < send; ++s){
    float4 c0 = x0, c1 = x1, c2 = x2;
    if (s + 1 < send){
      const float4* nx = (const float4*)(seq + ((size_t)nb * SEQLEN + s + 1) * DMODEL);
      x0 = nx[lane]; x1 = nx[64 + lane]; x2 = nx[128 + lane];
    }
    float sm = c0.x+c0.y+c0.z+c0.w + c1.x+c1.y+c1.z+c1.w + c2.x+c2.y+c2.z+c2.w;
    float qq = dot4f(c0,c0) + dot4f(c1,c1) + dot4f(c2,c2);
    float d0 = dot4f(q0[0],c0) + dot4f(q1[0],c1) + dot4f(q2[0],c2);
    float d1 = dot4f(q0[1],c0) + dot4f(q1[1],c1) + dot4f(q2[1],c2);
    float d2 = dot4f(q0[2],c0) + dot4f(q1[2],c1) + dot4f(q2[2],c2);
    sm = wsum64(sm); qq = wsum64(qq);
    d0 = wsum64(d0); d1 = wsum64(d1); d2 = wsum64(d2);
    float m = sm * (1.0f/DMODEL);
    float var = qq * (1.0f/DMODEL) - m * m;
    float r = rsqrtf(var + 1e-5f);
    float dt[3] = {d0, d1, d2};
    #pragma unroll
    for (int j = 0; j < 3; ++j){
      float score = r * (dt[j] - m * sqv[j]) + scv[j];
      if (score > mx[j] + 8.0f){           // defer-max rescale (rare)
        float f = __expf(mx[j] - score);
        den[j] *= f; cac[j] *= f;
        a0[j].x*=f; a0[j].y*=f; a0[j].z*=f; a0[j].w*=f;
        a1[j].x*=f; a1[j].y*=f; a1[j].z*=f; a1[j].w*=f;
        a2[j].x*=f; a2[j].y*=f; a2[j].z*=f; a2[j].w*=f;
        mx[j] = score;
      }
      float e = __expf(score - mx[j]);
      float er = e * r;
      a0[j].x = fmaf(er, c0.x, a0[j].x); a0[j].y = fmaf(er, c0.y, a0[j].y);
      a0[j].z = fmaf(er, c0.z, a0[j].z); a0[j].w = fmaf(er, c0.w, a0[j].w);
      a1[j].x = fmaf(er, c1.x, a1[j].x); a1[j].y = fmaf(er, c1.y, a1[j].y);
      a1[j].z = fmaf(er, c1.z, a1[j].z); a1[j].w = fmaf(er, c1.w, a1[j].w);
      a2[j].x = fmaf(er, c2.x, a2[j].x); a2[j].y = fmaf(er, c2.y, a2[j].y);
      a2[j].z = fmaf(er, c2.z, a2[j].z); a2[j].w = fmaf(er, c2.w, a2[j].w);
      den[j] += e;
      cac[j] = fmaf(er, m, cac[j]);
    }
  }
  #pragma unroll
  for (int j = 0; j < 3; ++j){
    float4* pa = (float4*)(Pacc + (pb + j) * DMODEL);
    pa[lane] = a0[j]; pa[64 + lane] = a1[j]; pa[128 + lane] = a2[j];
    if (lane == 0){ Pden[pb+j] = den[j]; Pc[pb+j] = cac[j]; Pmx[pb+j] = mx[j]; }
  }
}

// -------- combine chunk partials over ch and domains, apply seq-LN affine:
// wsum[b,h,d] = (sum_n vec_n - sum_n c_n)*snw + 3*snb --------
__global__ __launch_bounds__(256) void k_comb(const float* __restrict__ Pacc,
    const float* __restrict__ Pden, const float* __restrict__ Pc,
    const float* __restrict__ Pmx, const float* __restrict__ snw,
    const float* __restrict__ snb, float* __restrict__ wsum){
  int tid = blockIdx.x * 256 + threadIdx.x;   // NB*NHEAD*DMODEL
  int d = tid % DMODEL;
  int t = tid / DMODEL;
  int h = t % NHEAD;
  int b = t / NHEAD;
  float vec = 0.0f, csum = 0.0f;
  #pragma unroll
  for (int n = 0; n < NDOM; ++n){
    int nb = n*NB + b;
    size_t p0 = ((size_t)nb * NCH) * NHEAD + h;
    float m0 = Pmx[p0], m1 = Pmx[p0 + NHEAD], m2 = Pmx[p0 + 2*NHEAD], m3 = Pmx[p0 + 3*NHEAD];
    float M = fmaxf(fmaxf(m0, m1), fmaxf(m2, m3));
    float w0 = __expf(m0 - M), w1 = __expf(m1 - M), w2 = __expf(m2 - M), w3 = __expf(m3 - M);
    float D = w0*Pden[p0] + w1*Pden[p0+NHEAD] + w2*Pden[p0+2*NHEAD] + w3*Pden[p0+3*NHEAD];
    float inv = 1.0f / D;
    float V = w0*Pacc[p0*DMODEL + d] + w1*Pacc[(p0+NHEAD)*DMODEL + d]
            + w2*Pacc[(p0+2*NHEAD)*DMODEL + d] + w3*Pacc[(p0+3*NHEAD)*DMODEL + d];
    float C = w0*Pc[p0] + w1*Pc[p0+NHEAD] + w2*Pc[p0+2*NHEAD] + w3*Pc[p0+3*NHEAD];
    vec = fmaf(V, inv, vec);
    csum = fmaf(C, inv, csum);
  }
  wsum[tid] = (vec - csum) * snw[d] + 3.0f * snb[d];
}

// -------- ctxsum[b,he] = sum_d wsum[b,h,d]*Wv[he,d] + 3*bv[he], wave per 4 he --------
__global__ __launch_bounds__(256) void k_ctxv2(const float* __restrict__ wsum,
    const float* __restrict__ Wv, const float* __restrict__ bv, float* __restrict__ ctxsum){
  int gw = (blockIdx.x * 256 + threadIdx.x) >> 6;   // 8*192 waves
  int lane = threadIdx.x & 63;
  int sl = lane & 7, g = lane >> 3;
  int bg = gw / 192; int j0 = (gw - bg * 192) * 4;
  int h = j0 >> 6;
  const float4* a4 = (const float4*)(wsum + ((size_t)(bg*8 + g) * NHEAD + h) * DMODEL);
  const float4* w0 = (const float4*)(Wv + (size_t)(j0+0) * DMODEL);
  const float4* w1 = (const float4*)(Wv + (size_t)(j0+1) * DMODEL);
  const float4* w2 = (const float4*)(Wv + (size_t)(j0+2) * DMODEL);
  const float4* w3 = (const float4*)(Wv + (size_t)(j0+3) * DMODEL);
  float acc0 = 0, acc1 = 0, acc2 = 0, acc3 = 0;
  #pragma unroll 4
  for (int i = 0; i < DMODEL/32; ++i){
    float4 av = a4[i*8 + sl];
    acc0 += dot4f(av, w0[i*8 + sl]);
    acc1 += dot4f(av, w1[i*8 + sl]);
    acc2 += dot4f(av, w2[i*8 + sl]);
    acc3 += dot4f(av, w3[i*8 + sl]);
  }
  #pragma unroll
  for (int o = 1; o <= 4; o <<= 1){
    acc0 += __shfl_xor(acc0, o, 64);
    acc1 += __shfl_xor(acc1, o, 64);
    acc2 += __shfl_xor(acc2, o, 64);
    acc3 += __shfl_xor(acc3, o, 64);
  }
  if (sl == 0){
    float4 bb = *(const float4*)(bv + j0);
    float4 v = make_float4(acc0 + 3.0f*bb.x, acc1 + 3.0f*bb.y, acc2 + 3.0f*bb.z, acc3 + 3.0f*bb.w);
    *(float4*)(ctxsum + (size_t)(bg*8 + g) * DMODEL + j0) = v;
  }
}

// -------- gate + residual, wave per 4 cols: out = ctx + sigmoid([ctx,sctx]@Wg^T + gb)*sctx --------
__global__ __launch_bounds__(256) void k_gate2(const float* __restrict__ ctx,
    const float* __restrict__ sctx, const float* __restrict__ Wg,
    const float* __restrict__ gb, float* __restrict__ out){
  int gw = (blockIdx.x * 256 + threadIdx.x) >> 6;   // 8*192 waves
  int lane = threadIdx.x & 63;
  int sl = lane & 7, g = lane >> 3;
  int bg = gw / 192; int j0 = (gw - bg * 192) * 4;
  int row = bg*8 + g;
  const float4* c4 = (const float4*)(ctx + (size_t)row * DMODEL);
  const float4* s4 = (const float4*)(sctx + (size_t)row * DMODEL);
  const float4* wr0 = (const float4*)(Wg + (size_t)(j0+0) * 2 * DMODEL);
  const float4* wr1 = (const float4*)(Wg + (size_t)(j0+1) * 2 * DMODEL);
  const float4* wr2 = (const float4*)(Wg + (size_t)(j0+2) * 2 * DMODEL);
  const float4* wr3 = (const float4*)(Wg + (size_t)(j0+3) * 2 * DMODEL);
  float acc0 = 0, acc1 = 0, acc2 = 0, acc3 = 0;
  #pragma unroll 4
  for (int i = 0; i < DMODEL/32; ++i){
    float4 cv = c4[i*8 + sl], sv = s4[i*8 + sl];
    acc0 += dot4f(cv, wr0[i*8 + sl]) + dot4f(sv, wr0[192 + i*8 + sl]);
    acc1 += dot4f(cv, wr1[i*8 + sl]) + dot4f(sv, wr1[192 + i*8 + sl]);
    acc2 += dot4f(cv, wr2[i*8 + sl]) + dot4f(sv, wr2[192 + i*8 + sl]);
    acc3 += dot4f(cv, wr3[i*8 + sl]) + dot4f(sv, wr3[192 + i*8 + sl]);
  }
  #pragma unroll
  for (int o = 1; o <= 4; o <<= 1){
    acc0 += __shfl_xor(acc0, o, 64);
    acc1 += __shfl_xor(acc1, o, 64);
    acc2 += __shfl_xor(acc2, o, 64);
    acc3 += __shfl_xor(acc3, o, 64);
  }
  if (sl == 0){
    size_t o = (size_t)row * DMODEL + j0;
    float4 bb = *(const float4*)(gb + j0);
    float4 cc = *(const float4*)(ctx + o);
    float4 ss = *(const float4*)(sctx + o);
    float4 v;
    v.x = cc.x + ss.x / (1.0f + __expf(-(acc0 + bb.x)));
    v.y = cc.y + ss.y / (1.0f + __expf(-(acc1 + bb.y)));
    v.z = cc.z + ss.z / (1.0f + __expf(-(acc2 + bb.z)));
    v.w = cc.w + ss.w / (1.0f + __expf(-(acc3 + bb.w)));
    *(float4*)(out + o) = v;
  }
}

// -------- classifier final dot: out[b] = sum_j h2[b,j]*w2[j] + b2 --------
__global__ __launch_bounds__(256) void k_cls2(const float* __restrict__ h2,
    const float* __restrict__ w2, const float* __restrict__ b2, float* __restrict__ out){
  int b = blockIdx.x; int t = threadIdx.x;
  float acc = 0;
  for (int j = t; j < FFNH; j += 256) acc = fmaf(h2[(size_t)b*FFNH + j], w2[j], acc);
  acc = wsum64(acc);
  __shared__ float sh[4];
  if ((t & 63) == 0) sh[t >> 6] = acc;
  __syncthreads();
  if (t == 0) out[b] = sh[0] + sh[1] + sh[2] + sh[3] + b2[0];
}

extern "C" void kernel_launch(void* const* d_in, const int* in_sizes, int n_in,
                              void* d_out, int out_size, void* d_ws, size_t ws_size,
                              hipStream_t stream){
  const float* in_ctx = (const float*)d_in[0];
  const float* seq    = (const float*)d_in[1];
  const int*   lens   = (const int*)d_in[2];
  const float* qn_w   = (const float*)d_in[3];
  const float* qn_b   = (const float*)d_in[4];
  const float* sn_w   = (const float*)d_in[5];
  const float* sn_b   = (const float*)d_in[6];
  const float* in_w   = (const float*)d_in[7];
  const float* in_b   = (const float*)d_in[8];
  const float* out_w  = (const float*)d_in[9];
  const float* out_b  = (const float*)d_in[10];
  const float* gate_w = (const float*)d_in[11];
  const float* gate_b = (const float*)d_in[12];
  const float* fln_w  = (const float*)d_in[13];
  const float* fln_b  = (const float*)d_in[14];
  const float* fw1    = (const float*)d_in[15];
  const float* fb1    = (const float*)d_in[16];
  const float* fw2    = (const float*)d_in[17];
  const float* fb2    = (const float*)d_in[18];
  const float* on_w   = (const float*)d_in[19];
  const float* on_b   = (const float*)d_in[20];
  const float* cl_w   = (const float*)d_in[21];
  const float* cl_b   = (const float*)d_in[22];
  const float* cw1    = (const float*)d_in[23];
  const float* cb1    = (const float*)d_in[24];
  const float* cw2    = (const float*)d_in[25];
  const float* cb2    = (const float*)d_in[26];

  float* wsf = (float*)d_ws;
  size_t off = 0;
  auto alloc = [&](size_t n){ float* p = wsf + off; off += n; return p; };
  float* c0     = alloc((size_t)NB*DMODEL);
  float* c1     = alloc((size_t)NB*DMODEL);
  float* cmid   = alloc((size_t)NB*DMODEL);
  float* qln    = alloc((size_t)NB*DMODEL);
  float* qh     = alloc((size_t)NB*DMODEL);
  float* QW     = alloc((size_t)NB*NHEAD*DMODEL);
  float* SQWb   = alloc((size_t)NB*NHEAD);
  float* SCb    = alloc((size_t)NB*NHEAD);
  float* Pacc   = alloc((size_t)NBROWS*NCH*NHEAD*DMODEL);
  float* Pden   = alloc((size_t)NBROWS*NCH*NHEAD);
  float* Pc     = alloc((size_t)NBROWS*NCH*NHEAD);
  float* Pmx    = alloc((size_t)NBROWS*NCH*NHEAD);
  float* wsumb  = alloc((size_t)NB*NHEAD*DMODEL);
  float* ctxsum = alloc((size_t)NB*DMODEL);
  float* sctx   = alloc((size_t)NB*DMODEL);
  float* h0     = alloc((size_t)NB*DMODEL);
  float* h1     = alloc((size_t)NB*FFNH);
  (void)ws_size; (void)in_sizes; (void)n_in; (void)out_size;

  hipMemcpyAsync(c0, in_ctx, (size_t)NB*DMODEL*sizeof(float), hipMemcpyDeviceToDevice, stream);
  float* cur = c0; float* nxt = c1;

  for (int l = 0; l < NBLK; ++l){
    const float* Wq = in_w + (size_t)l * 3 * DMODEL * DMODEL;
    const float* Wk = Wq + (size_t)DMODEL * DMODEL;
    const float* Wv = Wq + (size_t)2 * DMODEL * DMODEL;
    const float* bq = in_b + (size_t)l * 3 * DMODEL;
    const float* bk = bq + DMODEL;
    const float* bv = bq + 2 * DMODEL;

    k_ln<<<16, 256, 0, stream>>>(cur, qn_w + l*DMODEL, qn_b + l*DMODEL, qln, NB);
    k_gemmW<DMODEL,DMODEL,0,false><<<384, 256, 0, stream>>>(qln, Wq, bq, nullptr, qh);
    k_qpr<<<192, 256, 0, stream>>>(qh, Wk, sn_w + l*DMODEL, sn_b + l*DMODEL, bk, QW, SQWb, SCb);
    k_attn<<<NBROWS*NCH, 256, 0, stream>>>(seq, lens, QW, SQWb, SCb, Pacc, Pden, Pc, Pmx);
    k_comb<<<(NB*NHEAD*DMODEL)/256, 256, 0, stream>>>(Pacc, Pden, Pc, Pmx, sn_w + l*DMODEL, sn_b + l*DMODEL, wsumb);
    k_ctxv2<<<384, 256, 0, stream>>>(wsumb, Wv, bv, ctxsum);
    k_gemmW<DMODEL,DMODEL,2,false><<<384, 256, 0, stream>>>(ctxsum, out_w + (size_t)l*DMODEL*DMODEL, out_b + l*DMODEL, nullptr, sctx);
    k_gate2<<<384, 256, 0, stream>>>(cur, sctx, gate_w + (size_t)l*DMODEL*2*DMODEL, gate_b + l*DMODEL, cmid);
    k_ln<<<16, 256, 0, stream>>>(cmid, fln_w + l*DMODEL, fln_b + l*DMODEL, h0, NB);
    k_gemmW<DMODEL,FFNH,1,false><<<1536, 256, 0, stream>>>(h0, fw1 + (size_t)l*FFNH*DMODEL, fb1 + l*FFNH, nullptr, h1);
    k_gemmW<FFNH,DMODEL,0,true><<<384, 256, 0, stream>>>(h1, fw2 + (size_t)l*DMODEL*FFNH, fb2 + l*DMODEL, cmid, nxt);
    float* t = cur; cur = nxt; nxt = t;
  }

  k_ln<<<16, 256, 0, stream>>>(cur, on_w, on_b, qln, NB);
  k_ln<<<16, 256, 0, stream>>>(qln, cl_w, cl_b, h0, NB);
  k_gemmW<DMODEL,FFNH,1,false><<<1536, 256, 0, stream>>>(h0, cw1, cb1, nullptr, h1);
  k_cls2<<<64, 256, 0, stream>>>(h1, cw2, cb2, (float*)d_out);
}